// Round 4
// baseline (53.862 us; speedup 1.0000x reference)
//
#include <hip/hip_runtime.h>
#include <hip/hip_bf16.h>

// Problem constants (B=16, N=1024, DIN=128, DH=256)
#define NB     16
#define NN     1024
#define NP1    1025
#define DIN    128
#define DH     256

#define OFF1   2099200                 // input_MASK offset (floats)
#define OFF2   2115600                 // bias_mat offset (floats)

#define NB_LUT   24                    // 6 codebook rows x 4 hidden-quarters
#define NB_COPY  256                   // feature copy
#define NB_MASK  16                    // mask rows
#define RPB      4                     // bias rows per block
#define NB_BIAS  (NB * NP1 / RPB)      // 4100
#define BIAS0    (NB_LUT + NB_COPY + NB_MASK)
#define GRID     (BIAS0 + NB_BIAS)
#define READY    0xFFFFFFu             // 24 producer bits

__global__ __launch_bounds__(256) void fused(
    const float* __restrict__ feat,   // (16,1024,128)
    const int* __restrict__ mask,     // (16,1024) bool->int32
    const int* __restrict__ dm,       // (16,1024,1024)
    const float* __restrict__ tst,    // (128,)
    const float* __restrict__ cb,     // (6,128)
    const float* __restrict__ W1,     // (128,256)
    const float* __restrict__ b1,     // (256,)
    const float* __restrict__ W2,     // (256,)
    const float* __restrict__ b2,     // (1,)
    float* __restrict__ out,
    float* __restrict__ part,         // d_ws[0..23]
    unsigned* __restrict__ flag)      // d_ws[24]
{
    const int bid = blockIdx.x;
    const int tid = threadIdx.x;

    if (bid < NB_LUT) {
        // ---- LUT producer: codebook row c, hidden units [q*64, q*64+64) ----
        const int c  = bid >> 2;
        const int q  = bid & 3;
        const int wv = tid >> 6;       // k-quarter (one per wave)
        const int tl = tid & 63;       // hidden unit within quarter
        const int t  = q * 64 + tl;
        const float* __restrict__ w1p = W1 + (size_t)(wv * 32) * DH + t;
        const float* __restrict__ cbp = cb + c * DIN + wv * 32;
        float acc = 0.f;
        #pragma unroll
        for (int j = 0; j < 32; ++j)              // 32 independent loads in flight
            acc = fmaf(cbp[j], w1p[(size_t)j * DH], acc);
        __shared__ float red[4][64];
        red[wv][tl] = acc;
        __syncthreads();
        if (tid < 64) {
            float s = red[0][tid] + red[1][tid] + red[2][tid] + red[3][tid];
            float h = fmaxf(s + b1[t], 0.f) * W2[t];
            #pragma unroll
            for (int off = 32; off; off >>= 1)
                h += __shfl_down(h, off);
            if (tid == 0) {
                __hip_atomic_store(part + bid, h, __ATOMIC_RELAXED,
                                   __HIP_MEMORY_SCOPE_AGENT);
                __hip_atomic_fetch_or(flag, 1u << bid, __ATOMIC_RELEASE,
                                      __HIP_MEMORY_SCOPE_AGENT);
            }
        }
    } else if (bid < NB_LUT + NB_COPY) {
        // ---- input_X copy (float4); runs during LUT window ----
        const int cid  = bid - NB_LUT;
        const int b    = cid >> 4;
        const int chnk = cid & 15;
        const float4* __restrict__ src =
            (const float4*)(feat + (size_t)b * (NN * DIN)) + (size_t)chnk * 2048;
        float4* __restrict__ dst =
            (float4*)(out + (size_t)b * (NP1 * DIN) + DIN) + (size_t)chnk * 2048;
        #pragma unroll
        for (int u = 0; u < 8; ++u)
            dst[tid + 256 * u] = src[tid + 256 * u];
        if (chnk == 0 && tid < 32) {
            ((float4*)(out + (size_t)b * (NP1 * DIN)))[tid] =
                ((const float4*)tst)[tid];
        }
    } else if (bid < BIAS0) {
        // ---- input_MASK row ----
        const int b = bid - (NB_LUT + NB_COPY);
        float* __restrict__ om = out + OFF1 + b * NP1;
        const int* __restrict__ mb = mask + (size_t)b * NN;
        if (tid == 0) om[0] = 1.0f;
        for (int j = tid; j < NN; j += 256)
            om[1 + j] = mb[j] ? 1.0f : 0.0f;
    } else {
        // ---- bias rows: prefetch dm -> spin on LUT -> transform+store ----
        const int bb = bid - BIAS0;
        const int g0 = bb * RPB;                  // flat row in [0,16400)
        int v0[RPB], v1[RPB], v2[RPB], v3[RPB], c0[RPB];
        #pragma unroll
        for (int k = 0; k < RPB; ++k) {
            const int g = g0 + k;
            const int b = g / NP1;
            const int i = g - b * NP1;
            const int* __restrict__ src =
                dm + (size_t)b * (NN * NN) + (size_t)(i == 0 ? 0 : i - 1) * NN;
            v0[k] = src[tid];
            v1[k] = src[tid + 256];
            v2[k] = src[tid + 512];
            v3[k] = src[tid + 768];
            if (tid == 0 && i > 0)
                c0[k] = dm[(size_t)b * (NN * NN) + (i - 1)];
        }

        __shared__ float sl[7];
        __shared__ float sp[NB_LUT];
        if (tid == 0) {
            while ((__hip_atomic_load(flag, __ATOMIC_ACQUIRE,
                                      __HIP_MEMORY_SCOPE_AGENT) & READY) != READY)
                __builtin_amdgcn_s_sleep(8);
        }
        __syncthreads();
        if (tid < NB_LUT)
            sp[tid] = __hip_atomic_load(part + tid, __ATOMIC_RELAXED,
                                        __HIP_MEMORY_SCOPE_AGENT);
        __syncthreads();
        if (tid < 6)
            sl[tid] = sp[tid * 4] + sp[tid * 4 + 1] + sp[tid * 4 + 2]
                    + sp[tid * 4 + 3] + b2[0];
        if (tid == 6) sl[6] = 0.f;
        __syncthreads();

        #pragma unroll
        for (int k = 0; k < RPB; ++k) {
            const int g = g0 + k;
            const int b = g / NP1;
            const int i = g - b * NP1;
            float* __restrict__ orow = out + OFF2 + (size_t)g * NP1;
            if (i == 0) {
                if (tid == 0) orow[0] = sl[0];    // D[0,0]=0 -> lut[0]
                int r;
                r = v0[k]; orow[1+tid]     = (r==9999)?sl[5]:(r<=3?sl[r+1]:sl[6]);
                r = v1[k]; orow[1+tid+256] = (r==9999)?sl[5]:(r<=3?sl[r+1]:sl[6]);
                r = v2[k]; orow[1+tid+512] = (r==9999)?sl[5]:(r<=3?sl[r+1]:sl[6]);
                r = v3[k]; orow[1+tid+768] = (r==9999)?sl[5]:(r<=3?sl[r+1]:sl[6]);
            } else {
                if (tid == 0) {
                    int r = c0[k];
                    orow[0] = (r==9999)?sl[5]:(r<=3?sl[r+1]:sl[6]);
                }
                int d;
                d = v0[k]; orow[1+tid]     = (d==9999)?sl[5]:(d<5?sl[d]:sl[6]);
                d = v1[k]; orow[1+tid+256] = (d==9999)?sl[5]:(d<5?sl[d]:sl[6]);
                d = v2[k]; orow[1+tid+512] = (d==9999)?sl[5]:(d<5?sl[d]:sl[6]);
                d = v3[k]; orow[1+tid+768] = (d==9999)?sl[5]:(d<5?sl[d]:sl[6]);
            }
        }
    }
}

extern "C" void kernel_launch(void* const* d_in, const int* in_sizes, int n_in,
                              void* d_out, int out_size, void* d_ws, size_t ws_size,
                              hipStream_t stream) {
    const float* feat = (const float*)d_in[0];
    const int*   mask = (const int*)d_in[1];
    const int*   dm   = (const int*)d_in[2];
    const float* tst  = (const float*)d_in[3];
    const float* cb   = (const float*)d_in[4];
    const float* W1   = (const float*)d_in[5];
    const float* b1   = (const float*)d_in[6];
    const float* W2   = (const float*)d_in[7];
    const float* b2   = (const float*)d_in[8];
    float*    out  = (float*)d_out;
    float*    part = (float*)d_ws;
    unsigned* flag = (unsigned*)d_ws + NB_LUT;

    fused<<<GRID, 256, 0, stream>>>(feat, mask, dm, tst, cb, W1, b1, W2, b2,
                                    out, part, flag);
}

// Round 5
// 43.063 us; speedup vs baseline: 1.2508x; 1.2508x over previous
//
#include <hip/hip_runtime.h>
#include <hip/hip_bf16.h>

// Problem constants (B=16, N=1024, DIN=128, DH=256)
#define NB     16
#define NN     1024
#define NP1    1025
#define DIN    128
#define DH     256

#define OFF1   2099200                 // input_MASK offset (floats)
#define OFF2   2115600                 // bias_mat offset (floats)

// Kernel A grid: 1 LUT block + 256 copy blocks + 16 mask blocks
#define A_COPY0  1
#define A_MASK0  (A_COPY0 + 256)
#define A_GRID   (A_MASK0 + NB)

// Kernel B: 8 bias rows per block
#define RPB      8
#define B_GRID   (NB * NP1 / RPB)      // 2050

// ---------------- Kernel A: LUT + input_X + input_MASK ----------------------
__global__ __launch_bounds__(256) void pre_kernel(
    const float* __restrict__ feat,   // (16,1024,128)
    const int* __restrict__ mask,     // (16,1024) bool->int32
    const float* __restrict__ tst,    // (128,)
    const float* __restrict__ cb,     // (6,128)
    const float* __restrict__ W1,     // (128,256)
    const float* __restrict__ b1,     // (256,)
    const float* __restrict__ W2,     // (256,)
    const float* __restrict__ b2,     // (1,)
    float* __restrict__ out,
    float* __restrict__ lut)          // d_ws[0..6]
{
    const int bid = blockIdx.x;
    const int tid = threadIdx.x;

    if (bid == 0) {
        // ---- LUT: one pass over k, 6 accumulators (one W1 load -> 6 FMA) ----
        const int t = tid;             // hidden unit
        float acc0 = 0.f, acc1 = 0.f, acc2 = 0.f, acc3 = 0.f, acc4 = 0.f, acc5 = 0.f;
        #pragma unroll 4
        for (int k = 0; k < DIN; ++k) {
            float w = W1[(size_t)k * DH + t];
            acc0 = fmaf(cb[0 * DIN + k], w, acc0);
            acc1 = fmaf(cb[1 * DIN + k], w, acc1);
            acc2 = fmaf(cb[2 * DIN + k], w, acc2);
            acc3 = fmaf(cb[3 * DIN + k], w, acc3);
            acc4 = fmaf(cb[4 * DIN + k], w, acc4);
            acc5 = fmaf(cb[5 * DIN + k], w, acc5);
        }
        const float bb = b1[t], w2 = W2[t];
        float h[6] = {
            fmaxf(acc0 + bb, 0.f) * w2, fmaxf(acc1 + bb, 0.f) * w2,
            fmaxf(acc2 + bb, 0.f) * w2, fmaxf(acc3 + bb, 0.f) * w2,
            fmaxf(acc4 + bb, 0.f) * w2, fmaxf(acc5 + bb, 0.f) * w2 };
        __shared__ float red[6][4];
        #pragma unroll
        for (int c = 0; c < 6; ++c) {
            float p = h[c];
            #pragma unroll
            for (int off = 32; off; off >>= 1)
                p += __shfl_down(p, off);
            if ((tid & 63) == 0) red[c][tid >> 6] = p;
        }
        __syncthreads();
        if (tid < 6)
            lut[tid] = red[tid][0] + red[tid][1] + red[tid][2] + red[tid][3] + b2[0];
        if (tid == 6) lut[6] = 0.f;
    } else if (bid < A_MASK0) {
        // ---- input_X copy (float4) ----
        const int cid  = bid - A_COPY0;
        const int b    = cid >> 4;
        const int chnk = cid & 15;
        const float4* __restrict__ src =
            (const float4*)(feat + (size_t)b * (NN * DIN)) + (size_t)chnk * 2048;
        float4* __restrict__ dst =
            (float4*)(out + (size_t)b * (NP1 * DIN) + DIN) + (size_t)chnk * 2048;
        #pragma unroll
        for (int u = 0; u < 8; ++u)
            dst[tid + 256 * u] = src[tid + 256 * u];
        if (chnk == 0 && tid < 32) {
            ((float4*)(out + (size_t)b * (NP1 * DIN)))[tid] =
                ((const float4*)tst)[tid];
        }
    } else {
        // ---- input_MASK row ----
        const int b = bid - A_MASK0;
        float* __restrict__ om = out + OFF1 + b * NP1;
        const int* __restrict__ mb = mask + (size_t)b * NN;
        if (tid == 0) om[0] = 1.0f;
        for (int j = tid; j < NN; j += 256)
            om[1 + j] = mb[j] ? 1.0f : 0.0f;
    }
}

// ---------------- Kernel B: bias_mat only ------------------------------------
__global__ __launch_bounds__(256) void bias_kernel(
    const int* __restrict__ dm,       // (16,1024,1024)
    const float* __restrict__ lut,    // d_ws[0..6]
    float* __restrict__ out)
{
    const int tid = threadIdx.x;
    __shared__ float sl[7];
    if (tid < 7) sl[tid] = lut[tid];
    __syncthreads();

    const int g0 = blockIdx.x * RPB;              // flat row in [0,16400)
    #pragma unroll
    for (int k = 0; k < RPB; ++k) {
        const int g = g0 + k;
        const int b = g / NP1;
        const int i = g - b * NP1;
        float* __restrict__ orow = out + OFF2 + (size_t)g * NP1;
        const int* __restrict__ dmb = dm + (size_t)b * (NN * NN);

        if (i == 0) {
            if (tid == 0) orow[0] = sl[0];        // D[0,0]=0 -> lut[0]
            int r0 = dmb[tid];
            int r1 = dmb[tid + 256];
            int r2 = dmb[tid + 512];
            int r3 = dmb[tid + 768];
            orow[1 + tid]       = (r0 == 9999) ? sl[5] : (r0 <= 3 ? sl[r0 + 1] : sl[6]);
            orow[1 + tid + 256] = (r1 == 9999) ? sl[5] : (r1 <= 3 ? sl[r1 + 1] : sl[6]);
            orow[1 + tid + 512] = (r2 == 9999) ? sl[5] : (r2 <= 3 ? sl[r2 + 1] : sl[6]);
            orow[1 + tid + 768] = (r3 == 9999) ? sl[5] : (r3 <= 3 ? sl[r3 + 1] : sl[6]);
        } else {
            if (tid == 0) {
                int r = dmb[i - 1];               // upd(dm[b,0,i-1]) -> col 0
                orow[0] = (r == 9999) ? sl[5] : (r <= 3 ? sl[r + 1] : sl[6]);
            }
            const int* __restrict__ dr = dmb + (size_t)(i - 1) * NN;
            int d0 = dr[tid];
            int d1 = dr[tid + 256];
            int d2 = dr[tid + 512];
            int d3 = dr[tid + 768];
            orow[1 + tid]       = (d0 == 9999) ? sl[5] : (d0 < 5 ? sl[d0] : sl[6]);
            orow[1 + tid + 256] = (d1 == 9999) ? sl[5] : (d1 < 5 ? sl[d1] : sl[6]);
            orow[1 + tid + 512] = (d2 == 9999) ? sl[5] : (d2 < 5 ? sl[d2] : sl[6]);
            orow[1 + tid + 768] = (d3 == 9999) ? sl[5] : (d3 < 5 ? sl[d3] : sl[6]);
        }
    }
}

extern "C" void kernel_launch(void* const* d_in, const int* in_sizes, int n_in,
                              void* d_out, int out_size, void* d_ws, size_t ws_size,
                              hipStream_t stream) {
    const float* feat = (const float*)d_in[0];
    const int*   mask = (const int*)d_in[1];
    const int*   dm   = (const int*)d_in[2];
    const float* tst  = (const float*)d_in[3];
    const float* cb   = (const float*)d_in[4];
    const float* W1   = (const float*)d_in[5];
    const float* b1   = (const float*)d_in[6];
    const float* W2   = (const float*)d_in[7];
    const float* b2   = (const float*)d_in[8];
    float* out = (float*)d_out;
    float* lut = (float*)d_ws;

    pre_kernel<<<A_GRID, 256, 0, stream>>>(feat, mask, tst, cb, W1, b1, W2, b2,
                                           out, lut);
    bias_kernel<<<B_GRID, 256, 0, stream>>>(dm, lut, out);
}

// Round 7
// 39.602 us; speedup vs baseline: 1.3601x; 1.0874x over previous
//
#include <hip/hip_runtime.h>
#include <hip/hip_bf16.h>

// Problem constants (B=16, N=1024, DIN=128, DH=256)
#define NB     16
#define NN     1024
#define NP1    1025
#define DIN    128
#define DH     256

#define OFF1   2099200                 // input_MASK offset (floats)
#define OFF2   2115600                 // bias_mat offset (floats)

#define RPB      4
#define NB_BIAS  (NB * NP1 / RPB)      // 4100 blocks, 4 bias rows each
#define NB_COPY  (NB * 16)             // 256 blocks: feature copy
#define NB_MASK  NB                    // 16 blocks: mask rows
#define NPART    24                    // 6 codebook rows x 4 hidden-quarters

typedef float vfloat4 __attribute__((ext_vector_type(4)));

// ---------------- Kernel A: 24-block MLP partials into d_ws -----------------
__global__ __launch_bounds__(256) void lut_kernel(
    const float* __restrict__ cb,   // (6,128)
    const float* __restrict__ W1,   // (128,256)
    const float* __restrict__ b1,   // (256,)
    const float* __restrict__ W2,   // (256,)
    float* __restrict__ part)       // d_ws[0..23]
{
    const int c  = blockIdx.x >> 2;    // codebook row
    const int q  = blockIdx.x & 3;     // hidden quarter
    const int wv = threadIdx.x >> 6;   // k-slice (one per wave)
    const int tl = threadIdx.x & 63;
    const int t  = q * 64 + tl;        // hidden unit
    const float* __restrict__ w1p = W1 + (size_t)(wv * 32) * DH + t;
    const float* __restrict__ cbp = cb + c * DIN + wv * 32;
    float acc = 0.f;
    #pragma unroll
    for (int j = 0; j < 32; ++j)       // 32 independent loads in flight
        acc = fmaf(cbp[j], w1p[(size_t)j * DH], acc);
    __shared__ float red[4][64];
    red[wv][tl] = acc;
    __syncthreads();
    if (threadIdx.x < 64) {
        const int th = q * 64 + threadIdx.x;
        float s = red[0][threadIdx.x] + red[1][threadIdx.x]
                + red[2][threadIdx.x] + red[3][threadIdx.x];
        float h = fmaxf(s + b1[th], 0.f) * W2[th];
        #pragma unroll
        for (int off = 32; off; off >>= 1)
            h += __shfl_down(h, off);
        if (threadIdx.x == 0) part[blockIdx.x] = h;
    }
}

// ---------------- Kernel B: bias + copy + mask (R3 structure) ---------------
__global__ __launch_bounds__(256) void main_kernel(
    const float* __restrict__ feat,          // (16,1024,128)
    const int* __restrict__ mask,            // (16,1024) bool->int32
    const int* __restrict__ dm,              // (16,1024,1024)
    const float* __restrict__ tst,           // (128,)
    const float* __restrict__ b2,            // (1,)
    const float* __restrict__ part,          // d_ws[0..23]
    float* __restrict__ out)
{
    const int bid = blockIdx.x;
    const int tid = threadIdx.x;

    if (bid < NB_BIAS) {
        // -------- 4 consecutive flat bias rows --------
        const int g0 = bid * RPB;
        // prefetch all 16 row values + border values first
        int va[RPB], vb[RPB], vc[RPB], vd[RPB], c0[RPB];
        #pragma unroll
        for (int k = 0; k < RPB; ++k) {
            const int g = g0 + k;
            const int b = g / NP1;
            const int i = g - b * NP1;
            const int* __restrict__ src =
                dm + (size_t)b * (NN * NN) + (size_t)(i == 0 ? 0 : i - 1) * NN;
            va[k] = __builtin_nontemporal_load(src + tid);
            vb[k] = __builtin_nontemporal_load(src + tid + 256);
            vc[k] = __builtin_nontemporal_load(src + tid + 512);
            vd[k] = __builtin_nontemporal_load(src + tid + 768);
            c0[k] = (tid == 0 && i > 0)
                  ? dm[(size_t)b * (NN * NN) + (i - 1)] : 0;
        }

        // build 7-entry LUT from the 24 partials
        __shared__ float sp[NPART];
        __shared__ float sl[7];
        if (tid < NPART) sp[tid] = part[tid];
        __syncthreads();
        if (tid < 6)
            sl[tid] = sp[4 * tid] + sp[4 * tid + 1] + sp[4 * tid + 2]
                    + sp[4 * tid + 3] + b2[0];
        if (tid == 6) sl[6] = 0.f;
        __syncthreads();

        #pragma unroll
        for (int k = 0; k < RPB; ++k) {
            const int g = g0 + k;
            const int b = g / NP1;
            const int i = g - b * NP1;
            float* __restrict__ orow = out + OFF2 + (size_t)g * NP1;
            if (i == 0) {
                if (tid == 0) __builtin_nontemporal_store(sl[0], orow);
                int r;
                r = va[k]; __builtin_nontemporal_store((r==9999)?sl[5]:(r<=3?sl[r+1]:sl[6]), orow+1+tid);
                r = vb[k]; __builtin_nontemporal_store((r==9999)?sl[5]:(r<=3?sl[r+1]:sl[6]), orow+1+tid+256);
                r = vc[k]; __builtin_nontemporal_store((r==9999)?sl[5]:(r<=3?sl[r+1]:sl[6]), orow+1+tid+512);
                r = vd[k]; __builtin_nontemporal_store((r==9999)?sl[5]:(r<=3?sl[r+1]:sl[6]), orow+1+tid+768);
            } else {
                if (tid == 0) {
                    int r = c0[k];
                    __builtin_nontemporal_store((r==9999)?sl[5]:(r<=3?sl[r+1]:sl[6]), orow);
                }
                int d;
                d = va[k]; __builtin_nontemporal_store((d==9999)?sl[5]:(d<5?sl[d]:sl[6]), orow+1+tid);
                d = vb[k]; __builtin_nontemporal_store((d==9999)?sl[5]:(d<5?sl[d]:sl[6]), orow+1+tid+256);
                d = vc[k]; __builtin_nontemporal_store((d==9999)?sl[5]:(d<5?sl[d]:sl[6]), orow+1+tid+512);
                d = vd[k]; __builtin_nontemporal_store((d==9999)?sl[5]:(d<5?sl[d]:sl[6]), orow+1+tid+768);
            }
        }
    } else if (bid < NB_BIAS + NB_COPY) {
        // -------- input_X copy (float4, non-temporal) --------
        const int cid  = bid - NB_BIAS;
        const int b    = cid >> 4;
        const int chnk = cid & 15;
        const vfloat4* __restrict__ src =
            (const vfloat4*)(feat + (size_t)b * (NN * DIN)) + (size_t)chnk * 2048;
        vfloat4* __restrict__ dst =
            (vfloat4*)(out + (size_t)b * (NP1 * DIN) + DIN) + (size_t)chnk * 2048;
        #pragma unroll
        for (int u = 0; u < 8; ++u) {
            vfloat4 v = __builtin_nontemporal_load(src + tid + 256 * u);
            __builtin_nontemporal_store(v, dst + tid + 256 * u);
        }
        if (chnk == 0 && tid < 32) {
            ((vfloat4*)(out + (size_t)b * (NP1 * DIN)))[tid] =
                ((const vfloat4*)tst)[tid];
        }
    } else {
        // -------- input_MASK row --------
        const int b = bid - (NB_BIAS + NB_COPY);
        float* __restrict__ om = out + OFF1 + b * NP1;
        const int* __restrict__ mb = mask + (size_t)b * NN;
        if (tid == 0) om[0] = 1.0f;
        for (int j = tid; j < NN; j += 256) {
            int m = __builtin_nontemporal_load(mb + j);
            __builtin_nontemporal_store(m ? 1.0f : 0.0f, om + 1 + j);
        }
    }
}

extern "C" void kernel_launch(void* const* d_in, const int* in_sizes, int n_in,
                              void* d_out, int out_size, void* d_ws, size_t ws_size,
                              hipStream_t stream) {
    const float* feat = (const float*)d_in[0];
    const int*   mask = (const int*)d_in[1];
    const int*   dm   = (const int*)d_in[2];
    const float* tst  = (const float*)d_in[3];
    const float* cb   = (const float*)d_in[4];
    const float* W1   = (const float*)d_in[5];
    const float* b1   = (const float*)d_in[6];
    const float* W2   = (const float*)d_in[7];
    const float* b2   = (const float*)d_in[8];
    float* out  = (float*)d_out;
    float* part = (float*)d_ws;

    lut_kernel<<<NPART, 256, 0, stream>>>(cb, W1, b1, W2, part);
    main_kernel<<<NB_BIAS + NB_COPY + NB_MASK, 256, 0, stream>>>(
        feat, mask, dm, tst, b2, part, out);
}

// Round 8
// 33.373 us; speedup vs baseline: 1.6139x; 1.1866x over previous
//
#include <hip/hip_runtime.h>
#include <hip/hip_bf16.h>

// Problem constants (B=16, N=1024, DIN=128, DH=256)
#define NB     16
#define NN     1024
#define NP1    1025
#define DIN    128
#define DH     256

#define OFF1   2099200                 // input_MASK offset (floats)
#define OFF2   2115600                 // bias_mat offset (floats)

#define RPB      4
#define NB_BIAS  (NB * NP1 / RPB)      // 4100 blocks, 4 bias rows each
#define NB_COPY  (NB * 16)             // 256 copy blocks
#define NB_MASK  NB                    // 16 mask blocks
#define BIAS0    (NB_COPY + NB_MASK)   // copy+mask first, bias after
#define NPART    24                    // 6 codebook rows x 4 hidden-quarters

// ---------------- Kernel A: 24-block MLP partials into d_ws -----------------
__global__ __launch_bounds__(256) void lut_kernel(
    const float* __restrict__ cb,   // (6,128)
    const float* __restrict__ W1,   // (128,256)
    const float* __restrict__ b1,   // (256,)
    const float* __restrict__ W2,   // (256,)
    float* __restrict__ part)       // d_ws[0..23]
{
    const int c  = blockIdx.x >> 2;    // codebook row
    const int q  = blockIdx.x & 3;     // hidden quarter
    const int wv = threadIdx.x >> 6;   // k-slice (one per wave)
    const int tl = threadIdx.x & 63;
    const int t  = q * 64 + tl;        // hidden unit
    const float* __restrict__ w1p = W1 + (size_t)(wv * 32) * DH + t;
    const float* __restrict__ cbp = cb + c * DIN + wv * 32;
    float acc = 0.f;
    #pragma unroll
    for (int j = 0; j < 32; ++j)       // 32 independent loads in flight
        acc = fmaf(cbp[j], w1p[(size_t)j * DH], acc);
    __shared__ float red[4][64];
    red[wv][tl] = acc;
    __syncthreads();
    if (threadIdx.x < 64) {
        const int th = q * 64 + threadIdx.x;
        float s = red[0][threadIdx.x] + red[1][threadIdx.x]
                + red[2][threadIdx.x] + red[3][threadIdx.x];
        float h = fmaxf(s + b1[th], 0.f) * W2[th];
        #pragma unroll
        for (int off = 32; off; off >>= 1)
            h += __shfl_down(h, off);
        if (threadIdx.x == 0) part[blockIdx.x] = h;
    }
}

// ---------------- Kernel B: copy + mask + bias (exact R3 bodies) ------------
__global__ __launch_bounds__(256) void main_kernel(
    const float* __restrict__ feat,          // (16,1024,128)
    const int* __restrict__ mask,            // (16,1024) bool->int32
    const int* __restrict__ dm,              // (16,1024,1024)
    const float* __restrict__ tst,           // (128,)
    const float* __restrict__ b2,            // (1,)
    const float* __restrict__ part,          // d_ws[0..23]
    float* __restrict__ out)
{
    const int bid = blockIdx.x;
    const int tid = threadIdx.x;

    if (bid < NB_COPY) {
        // -------- input_X copy (float4) — fat blocks first --------
        const int b    = bid >> 4;
        const int chnk = bid & 15;
        const float4* __restrict__ src =
            (const float4*)(feat + (size_t)b * (NN * DIN)) + (size_t)chnk * 2048;
        float4* __restrict__ dst =
            (float4*)(out + (size_t)b * (NP1 * DIN) + DIN) + (size_t)chnk * 2048;
        #pragma unroll
        for (int u = 0; u < 8; ++u)
            dst[tid + 256 * u] = src[tid + 256 * u];
        if (chnk == 0 && tid < 32) {
            ((float4*)(out + (size_t)b * (NP1 * DIN)))[tid] =
                ((const float4*)tst)[tid];
        }
    } else if (bid < BIAS0) {
        // -------- input_MASK row --------
        const int b = bid - NB_COPY;
        float* __restrict__ om = out + OFF1 + b * NP1;
        const int* __restrict__ mb = mask + (size_t)b * NN;
        if (tid == 0) om[0] = 1.0f;
        for (int j = tid; j < NN; j += 256)
            om[1 + j] = mb[j] ? 1.0f : 0.0f;
    } else {
        // -------- 4 consecutive flat bias rows (exact R3 body) --------
        __shared__ float sp[NPART];
        __shared__ float sl[7];
        if (tid < NPART) sp[tid] = part[tid];
        __syncthreads();
        if (tid < 6)
            sl[tid] = sp[4 * tid] + sp[4 * tid + 1] + sp[4 * tid + 2]
                    + sp[4 * tid + 3] + b2[0];
        if (tid == 6) sl[6] = 0.f;
        __syncthreads();

        const int g0 = (bid - BIAS0) * RPB;  // flat row index in [0, 16400)
        #pragma unroll
        for (int k = 0; k < RPB; ++k) {
            const int g = g0 + k;
            const int b = g / NP1;
            const int i = g - b * NP1;
            float* __restrict__ orow = out + OFF2 + (size_t)g * NP1;
            const int* __restrict__ dmb = dm + (size_t)b * (NN * NN);

            if (i == 0) {
                if (tid == 0) orow[0] = sl[0];
                int r0 = dmb[tid];
                int r1 = dmb[tid + 256];
                int r2 = dmb[tid + 512];
                int r3 = dmb[tid + 768];
                orow[1 + tid]       = (r0 == 9999) ? sl[5] : (r0 <= 3 ? sl[r0 + 1] : sl[6]);
                orow[1 + tid + 256] = (r1 == 9999) ? sl[5] : (r1 <= 3 ? sl[r1 + 1] : sl[6]);
                orow[1 + tid + 512] = (r2 == 9999) ? sl[5] : (r2 <= 3 ? sl[r2 + 1] : sl[6]);
                orow[1 + tid + 768] = (r3 == 9999) ? sl[5] : (r3 <= 3 ? sl[r3 + 1] : sl[6]);
            } else {
                if (tid == 0) {
                    int r = dmb[i - 1];
                    orow[0] = (r == 9999) ? sl[5] : (r <= 3 ? sl[r + 1] : sl[6]);
                }
                const int* __restrict__ dr = dmb + (size_t)(i - 1) * NN;
                int d0 = dr[tid];
                int d1 = dr[tid + 256];
                int d2 = dr[tid + 512];
                int d3 = dr[tid + 768];
                orow[1 + tid]       = (d0 == 9999) ? sl[5] : (d0 < 5 ? sl[d0] : sl[6]);
                orow[1 + tid + 256] = (d1 == 9999) ? sl[5] : (d1 < 5 ? sl[d1] : sl[6]);
                orow[1 + tid + 512] = (d2 == 9999) ? sl[5] : (d2 < 5 ? sl[d2] : sl[6]);
                orow[1 + tid + 768] = (d3 == 9999) ? sl[5] : (d3 < 5 ? sl[d3] : sl[6]);
            }
        }
    }
}

extern "C" void kernel_launch(void* const* d_in, const int* in_sizes, int n_in,
                              void* d_out, int out_size, void* d_ws, size_t ws_size,
                              hipStream_t stream) {
    const float* feat = (const float*)d_in[0];
    const int*   mask = (const int*)d_in[1];
    const int*   dm   = (const int*)d_in[2];
    const float* tst  = (const float*)d_in[3];
    const float* cb   = (const float*)d_in[4];
    const float* W1   = (const float*)d_in[5];
    const float* b1   = (const float*)d_in[6];
    const float* W2   = (const float*)d_in[7];
    const float* b2   = (const float*)d_in[8];
    float* out  = (float*)d_out;
    float* part = (float*)d_ws;

    lut_kernel<<<NPART, 256, 0, stream>>>(cb, W1, b1, W2, part);
    main_kernel<<<BIAS0 + NB_BIAS, 256, 0, stream>>>(
        feat, mask, dm, tst, b2, part, out);
}